// Round 5
// baseline (281.869 us; speedup 1.0000x reference)
//
#include <hip/hip_runtime.h>

typedef unsigned char u8;
typedef unsigned short u16;
typedef float f32x4 __attribute__((ext_vector_type(4)));
typedef long l2 __attribute__((ext_vector_type(2)));

#define NROWS 16384
#define DIM 128

// exp(-2*sim) = exp2(sim * -2*log2(e)); scale folded into normalized B rows.
#define NEG2LOG2E -2.8853900817779268f

// One wave per row: L2-normalize rows of a and b, emit fp8 e4m3 (OCP).
// B rows pre-scaled by -2*log2(e) so GEMM output feeds exp2 directly.
__global__ __launch_bounds__(256) void norm_kernel(
    const float* __restrict__ a, const float* __restrict__ b,
    u8* __restrict__ aO, u8* __restrict__ bO)
{
    int tid  = threadIdx.x;
    int lane = tid & 63;
    int w    = tid >> 6;
    long row = (long)blockIdx.x * 4 + w;

    const float2 va = ((const float2*)(a + row * DIM))[lane];
    float sa = va.x * va.x + va.y * va.y;
    #pragma unroll
    for (int off = 32; off; off >>= 1) sa += __shfl_xor(sa, off, 64);
    float inva = 1.0f / fmaxf(sqrtf(sa), 1e-12f);
    unsigned int pa = (unsigned int)__builtin_amdgcn_cvt_pk_fp8_f32(
        va.x * inva, va.y * inva, 0, false);
    ((u16*)(aO + row * DIM))[lane] = (u16)(pa & 0xffffu);

    const float2 vb = ((const float2*)(b + row * DIM))[lane];
    float sb = vb.x * vb.x + vb.y * vb.y;
    #pragma unroll
    for (int off = 32; off; off >>= 1) sb += __shfl_xor(sb, off, 64);
    float invb = NEG2LOG2E / fmaxf(sqrtf(sb), 1e-12f);
    unsigned int pb = (unsigned int)__builtin_amdgcn_cvt_pk_fp8_f32(
        vb.x * invb, vb.y * invb, 0, false);
    ((u16*)(bO + row * DIM))[lane] = (u16)(pb & 0xffffu);
}

// 128x128 C-tile per block; 4 waves in 2x2; 4x4 16x16x32 fp8 MFMA per wave.
// A/B tiles are 16 KB fp8 slabs (row = 128 B), staged via global_load_lds
// width-16 with a 16-B-granule xor swizzle: LDS granule g of row m holds
// global granule g^(m&7).
//
// k-permutation trick: the GEMM k-order is arbitrary (same permutation on A
// and B preserves the dot product). We map MFMA k-slot (ks,q,j) -> global
// k = q*32 + ks*8 + j, so each lane's 4 ks-fragments are a contiguous 32-B
// span: two ds_read_b128 per matrix per mi (b128 + xor swizzle = the pattern
// measured conflict-free in the bf16 version). Per-h address = base ^ (h<<4).
__global__ __launch_bounds__(256, 4) void gemm_kernel(
    const u8* __restrict__ A, const u8* __restrict__ B,
    const int* __restrict__ labels, float* __restrict__ out)
{
    __shared__ u8 sAB[32768];   // A tile @0, B tile @16384

    int tid  = threadIdx.x;
    int lane = tid & 63;
    int w    = tid >> 6;
    int wr   = w >> 1;
    int wc   = w & 1;
    int mrow = lane & 15;
    int q    = lane >> 4;

    int rowBase = blockIdx.y * 128;
    int colBase = blockIdx.x * 128;

    // --- staging: 2 x 16 KB, 4 iters x 256 threads x 16 B each, swizzled src ---
    {
        int m0 = tid >> 3;                  // row within 32-row group
        int p0 = tid & 7;                   // 16-B granule within row
        int srcOff = m0 * 128 + ((p0 ^ (m0 & 7)) << 4);
        const u8* gpA = A + (size_t)rowBase * DIM + srcOff;
        const u8* gpB = B + (size_t)colBase * DIM + srcOff;
        u8* lp = &sAB[(size_t)tid * 16 - (size_t)lane * 16];  // wave-uniform base
        #pragma unroll
        for (int iter = 0; iter < 4; iter++) {
            __builtin_amdgcn_global_load_lds(
                (const __attribute__((address_space(1))) void*)gpA,
                (__attribute__((address_space(3))) void*)lp, 16, 0, 0);
            __builtin_amdgcn_global_load_lds(
                (const __attribute__((address_space(1))) void*)gpB,
                (__attribute__((address_space(3))) void*)(lp + 16384), 16, 0, 0);
            gpA += 4096; gpB += 4096; lp += 4096;   // 32 rows * 128 B
        }
    }

    // Fragment LDS byte offsets (h=0): granule (q*2)^(row&7) of the row.
    int aOff[4], bOff[4];
    #pragma unroll
    for (int mi = 0; mi < 4; mi++) {
        int m = wr * 64 + mi * 16 + mrow;
        aOff[mi] = m * 128 + (((q << 1) ^ (m & 7)) << 4);
        int n = wc * 64 + mi * 16 + mrow;
        bOff[mi] = 16384 + n * 128 + (((q << 1) ^ (n & 7)) << 4);
    }

    f32x4 acc[4][4];
    #pragma unroll
    for (int mi = 0; mi < 4; mi++)
        #pragma unroll
        for (int ni = 0; ni < 4; ni++)
            acc[mi][ni] = (f32x4){0.f, 0.f, 0.f, 0.f};

    __syncthreads();

    #pragma unroll
    for (int h = 0; h < 2; h++) {
        l2 aF[4], bF[4];
        int x = h << 4;
        #pragma unroll
        for (int mi = 0; mi < 4; mi++) {
            aF[mi] = *(const l2*)(sAB + (aOff[mi] ^ x));
            bF[mi] = *(const l2*)(sAB + (bOff[mi] ^ x));
        }
        #pragma unroll
        for (int mi = 0; mi < 4; mi++)
            #pragma unroll
            for (int ni = 0; ni < 4; ni++) {
                acc[mi][ni] = __builtin_amdgcn_mfma_f32_16x16x32_fp8_fp8(
                    aF[mi][0], bF[ni][0], acc[mi][ni], 0, 0, 0);
                acc[mi][ni] = __builtin_amdgcn_mfma_f32_16x16x32_fp8_fp8(
                    aF[mi][1], bF[ni][1], acc[mi][ni], 0, 0, 0);
            }
    }

    // Labels loaded after MFMA (keeps MFMA-phase register pressure < 128).
    int iBase = rowBase + wr * 64 + q * 4;
    int jBase = colBase + wc * 64 + mrow;
    int li[16], lj[4];
    #pragma unroll
    for (int mi = 0; mi < 4; mi++)
        #pragma unroll
        for (int r = 0; r < 4; r++)
            li[mi * 4 + r] = labels[iBase + mi * 16 + r];
    #pragma unroll
    for (int ni = 0; ni < 4; ni++)
        lj[ni] = labels[jBase + ni * 16];

    // Epilogue: acc already = -2*log2e*sim; exp2 + label mask + local sum.
    float s0 = 0.0f, s1 = 0.0f;
    #pragma unroll
    for (int mi = 0; mi < 4; mi++)
        #pragma unroll
        for (int ni = 0; ni < 4; ni++)
            #pragma unroll
            for (int r = 0; r < 4; r++) {
                float e = __builtin_amdgcn_exp2f(acc[mi][ni][r]);
                float m = (li[mi * 4 + r] != lj[ni]) ? e : 0.0f;
                if (r & 1) s1 += m; else s0 += m;
            }
    float s = s0 + s1;

    #pragma unroll
    for (int off = 32; off; off >>= 1) s += __shfl_xor(s, off, 64);

    __syncthreads();                       // done with sAB — reuse for reduction
    float* red = (float*)sAB;
    if (lane == 0) red[w] = s;
    __syncthreads();
    if (tid == 0) {
        constexpr float SCALE = (float)(1.0 / (16384.0 * 16383.0));
        float t = (red[0] + red[1]) + (red[2] + red[3]);
        atomicAdd(out, t * SCALE);
    }
}

extern "C" void kernel_launch(void* const* d_in, const int* in_sizes, int n_in,
                              void* d_out, int out_size, void* d_ws, size_t ws_size,
                              hipStream_t stream) {
    const float* self_p = (const float*)d_in[0];
    const float* pos_p  = (const float*)d_in[1];
    const int*   labels = (const int*)d_in[2];
    float* out = (float*)d_out;

    u8* aB = (u8*)d_ws;                         // 2 MB fp8 normalized self
    u8* bB = aB + (size_t)NROWS * DIM;          // 2 MB fp8 normalized pos (pre-scaled)

    hipMemsetAsync(out, 0, sizeof(float), stream);
    norm_kernel<<<NROWS / 4, 256, 0, stream>>>(self_p, pos_p, aB, bB);
    gemm_kernel<<<dim3(128, 128), 256, 0, stream>>>(aB, bB, labels, out);
}

// Round 6
// 129.226 us; speedup vs baseline: 2.1812x; 2.1812x over previous
//
#include <hip/hip_runtime.h>

typedef unsigned char u8;
typedef unsigned short u16;
typedef float f32x4 __attribute__((ext_vector_type(4)));
typedef long l2 __attribute__((ext_vector_type(2)));

#define NROWS 16384
#define DIM 128

// exp(-2*sim) = exp2(sim * -2*log2(e)); scale folded into normalized B rows.
#define NEG2LOG2E -2.8853900817779268f

// One wave per row: L2-normalize rows of a and b, emit fp8 e4m3 (OCP).
// B rows pre-scaled by -2*log2(e) so GEMM output feeds exp2 directly.
__global__ __launch_bounds__(256) void norm_kernel(
    const float* __restrict__ a, const float* __restrict__ b,
    u8* __restrict__ aO, u8* __restrict__ bO)
{
    int tid  = threadIdx.x;
    int lane = tid & 63;
    int w    = tid >> 6;
    long row = (long)blockIdx.x * 4 + w;

    const float2 va = ((const float2*)(a + row * DIM))[lane];
    float sa = va.x * va.x + va.y * va.y;
    #pragma unroll
    for (int off = 32; off; off >>= 1) sa += __shfl_xor(sa, off, 64);
    float inva = 1.0f / fmaxf(sqrtf(sa), 1e-12f);
    unsigned int pa = (unsigned int)__builtin_amdgcn_cvt_pk_fp8_f32(
        va.x * inva, va.y * inva, 0, false);
    ((u16*)(aO + row * DIM))[lane] = (u16)(pa & 0xffffu);

    const float2 vb = ((const float2*)(b + row * DIM))[lane];
    float sb = vb.x * vb.x + vb.y * vb.y;
    #pragma unroll
    for (int off = 32; off; off >>= 1) sb += __shfl_xor(sb, off, 64);
    float invb = NEG2LOG2E / fmaxf(sqrtf(sb), 1e-12f);
    unsigned int pb = (unsigned int)__builtin_amdgcn_cvt_pk_fp8_f32(
        vb.x * invb, vb.y * invb, 0, false);
    ((u16*)(bO + row * DIM))[lane] = (u16)(pb & 0xffffu);
}

// Each block: 128 rows x 512 cols = 4 column-tiles of 128x128.
// A tile (16 KB) staged once, A-fragments held register-resident (32 VGPRs).
// B double-buffered (2 x 16 KB): loop = [issue DMA B_{t+1}] -> compute tile t
// -> barrier. The vmcnt(0) drain at the barrier is ~free: the prefetch had
// the whole MFMA+exp phase (~1000 cyc) in flight.
// Staging swizzle (row = 128 B = 8 granules): LDS granule g of row m holds
// global granule g^(m&7). Fragment (16 B, lane(mrow,q), half h) at byte
// m*128 + (((q*2)^(m&7))<<4) ^ (h<<4). k-permutation (same on A and B)
// keeps each lane's k-span contiguous -> ds_read_b128.
__global__ __launch_bounds__(256, 3) void gemm_kernel(
    const u8* __restrict__ A, const u8* __restrict__ B,
    const int* __restrict__ labels, float* __restrict__ partials)
{
    __shared__ u8 sA[16384];
    __shared__ u8 sB[2][16384];

    int tid  = threadIdx.x;
    int lane = tid & 63;
    int w    = tid >> 6;
    int wr   = w >> 1;
    int wc   = w & 1;
    int mrow = lane & 15;
    int q    = lane >> 4;

    int rowBase = blockIdx.y * 128;      // grid (32,128): x = column group
    int colBase = blockIdx.x * 512;

    // Staging pattern (identical for A and every B tile).
    int m0 = tid >> 3;                   // row within 32-row group
    int p0 = tid & 7;                    // 16-B granule within row
    int srcOff = m0 * 128 + ((p0 ^ (m0 & 7)) << 4);
    int ldsOff = (tid - lane) * 16;      // wave-uniform base for global_load_lds

    const u8* gA = A + (size_t)rowBase * DIM + srcOff;
    const u8* gB = B + (size_t)colBase * DIM + srcOff;

    // Stage A (16 KB) + B tile 0 (16 KB).
    {
        const u8* gpA = gA;
        const u8* gpB = gB;
        u8* lpA = &sA[ldsOff];
        u8* lpB = &sB[0][ldsOff];
        #pragma unroll
        for (int it = 0; it < 4; it++) {
            __builtin_amdgcn_global_load_lds(
                (const __attribute__((address_space(1))) void*)gpA,
                (__attribute__((address_space(3))) void*)lpA, 16, 0, 0);
            __builtin_amdgcn_global_load_lds(
                (const __attribute__((address_space(1))) void*)gpB,
                (__attribute__((address_space(3))) void*)lpB, 16, 0, 0);
            gpA += 4096; gpB += 4096; lpA += 4096; lpB += 4096;
        }
    }

    // Row labels (fixed for the whole block) — overlap with DMA.
    int iBase = rowBase + wr * 64 + q * 4;
    int li[16];
    #pragma unroll
    for (int mi = 0; mi < 4; mi++)
        #pragma unroll
        for (int r = 0; r < 4; r++)
            li[mi * 4 + r] = labels[iBase + mi * 16 + r];

    // Fragment LDS byte offsets (h=0); per-h address = base ^ (h<<4).
    int aOff[4], bOff[4];
    #pragma unroll
    for (int mi = 0; mi < 4; mi++) {
        int m = wr * 64 + mi * 16 + mrow;
        aOff[mi] = m * 128 + (((q << 1) ^ (m & 7)) << 4);
        int n = wc * 64 + mi * 16 + mrow;
        bOff[mi] = n * 128 + (((q << 1) ^ (n & 7)) << 4);
    }

    __syncthreads();   // A + B0 resident

    // A fragments register-resident for all 4 tiles (32 VGPRs).
    l2 aF[2][4];
    #pragma unroll
    for (int h = 0; h < 2; h++)
        #pragma unroll
        for (int mi = 0; mi < 4; mi++)
            aF[h][mi] = *(const l2*)(sA + (aOff[mi] ^ (h << 4)));

    float s = 0.0f;

    #pragma unroll
    for (int jt = 0; jt < 4; jt++) {
        // Prefetch next B tile into the other buffer (in flight during compute).
        if (jt < 3) {
            const u8* gp = gB + (jt + 1) * (128 * DIM);
            u8* lp = &sB[(jt + 1) & 1][ldsOff];
            #pragma unroll
            for (int it = 0; it < 4; it++) {
                __builtin_amdgcn_global_load_lds(
                    (const __attribute__((address_space(1))) void*)gp,
                    (__attribute__((address_space(3))) void*)lp, 16, 0, 0);
                gp += 4096; lp += 4096;
            }
        }

        // Column labels for this tile (L1-hot, hidden under MFMA).
        int jBase = colBase + jt * 128 + wc * 64 + mrow;
        int lj[4];
        #pragma unroll
        for (int ni = 0; ni < 4; ni++)
            lj[ni] = labels[jBase + ni * 16];

        const u8* sb = sB[jt & 1];
        f32x4 acc[4][4];
        #pragma unroll
        for (int mi = 0; mi < 4; mi++)
            #pragma unroll
            for (int ni = 0; ni < 4; ni++)
                acc[mi][ni] = (f32x4){0.f, 0.f, 0.f, 0.f};

        #pragma unroll
        for (int h = 0; h < 2; h++) {
            l2 bF[4];
            #pragma unroll
            for (int ni = 0; ni < 4; ni++)
                bF[ni] = *(const l2*)(sb + (bOff[ni] ^ (h << 4)));
            #pragma unroll
            for (int mi = 0; mi < 4; mi++)
                #pragma unroll
                for (int ni = 0; ni < 4; ni++) {
                    acc[mi][ni] = __builtin_amdgcn_mfma_f32_16x16x32_fp8_fp8(
                        aF[h][mi][0], bF[ni][0], acc[mi][ni], 0, 0, 0);
                    acc[mi][ni] = __builtin_amdgcn_mfma_f32_16x16x32_fp8_fp8(
                        aF[h][mi][1], bF[ni][1], acc[mi][ni], 0, 0, 0);
                }
        }

        // Epilogue: acc = -2*log2e*sim; exp2 + label mask, accumulate in s.
        float s0 = 0.0f, s1 = 0.0f;
        #pragma unroll
        for (int mi = 0; mi < 4; mi++)
            #pragma unroll
            for (int ni = 0; ni < 4; ni++)
                #pragma unroll
                for (int r = 0; r < 4; r++) {
                    float e = __builtin_amdgcn_exp2f(acc[mi][ni][r]);
                    float m = (li[mi * 4 + r] != lj[ni]) ? e : 0.0f;
                    if (r & 1) s1 += m; else s0 += m;
                }
        s += s0 + s1;

        // All waves done reading sB[jt&1] before it is overwritten next iter;
        // also drains the (long-in-flight) prefetch DMA.
        __syncthreads();
    }

    #pragma unroll
    for (int off = 32; off; off >>= 1) s += __shfl_xor(s, off, 64);

    float* red = (float*)sA;             // sA unused since A-frag preload
    if (lane == 0) red[w] = s;
    __syncthreads();
    if (tid == 0) {
        constexpr float SCALE = (float)(1.0 / (16384.0 * 16383.0));
        float t = (red[0] + red[1]) + (red[2] + red[3]);
        partials[blockIdx.y * 32 + blockIdx.x] = t * SCALE;
    }
}

__global__ __launch_bounds__(256) void reduce_kernel(
    const float* __restrict__ partials, float* __restrict__ out)
{
    int tid = threadIdx.x;
    const float4* p4 = (const float4*)partials;
    float s = 0.0f;
    #pragma unroll 4
    for (int i = tid; i < 1024; i += 256) {
        float4 v = p4[i];
        s += (v.x + v.y) + (v.z + v.w);
    }
    #pragma unroll
    for (int off = 32; off; off >>= 1) s += __shfl_xor(s, off, 64);
    __shared__ float red[4];
    if ((tid & 63) == 0) red[tid >> 6] = s;
    __syncthreads();
    if (tid == 0) out[0] = (red[0] + red[1]) + (red[2] + red[3]);
}

extern "C" void kernel_launch(void* const* d_in, const int* in_sizes, int n_in,
                              void* d_out, int out_size, void* d_ws, size_t ws_size,
                              hipStream_t stream) {
    const float* self_p = (const float*)d_in[0];
    const float* pos_p  = (const float*)d_in[1];
    const int*   labels = (const int*)d_in[2];
    float* out = (float*)d_out;

    u8* aB = (u8*)d_ws;                         // 2 MB fp8 normalized self
    u8* bB = aB + (size_t)NROWS * DIM;          // 2 MB fp8 normalized pos (pre-scaled)
    float* partials = (float*)(bB + (size_t)NROWS * DIM);  // 16 KB

    norm_kernel<<<NROWS / 4, 256, 0, stream>>>(self_p, pos_p, aB, bB);
    gemm_kernel<<<dim3(32, 128), 256, 0, stream>>>(aB, bB, labels, partials);
    reduce_kernel<<<1, 256, 0, stream>>>(partials, out);
}